// Round 6
// baseline (150.701 us; speedup 1.0000x reference)
//
#include <hip/hip_runtime.h>

#define NN 50000
#define KK 20

// Pool in TWO channel groups of 32 for XCD slicing: g_pool[grp][side][n*32+ch]
// bf16. Slice (A+B) = 6.4 MB; grp = bx&1 pins grp 0 -> XCDs {0,2,4,6},
// grp 1 -> {1,3,5,7} (bx%8 round-robin mapping validated by R4's FETCH drop,
// hit-rate model validated by R5's FETCH = 110 MB).
__device__ __align__(256) ushort g_pool[2][2][NN * 32];   // 12.8 MB
__device__ __align__(256) float  g_sup[NN * KK];          // 4 MB

static __device__ __forceinline__ ushort f2bf(float f) {
    unsigned int u = __float_as_uint(f);
    unsigned int r = (u + 0x7FFFu + ((u >> 16) & 1u)) >> 16;   // RNE
    return (ushort)r;
}
static __device__ __forceinline__ float bfl(unsigned int u) {   // low bf16 -> f32
    return __uint_as_float(u << 16);
}
static __device__ __forceinline__ float bfh(unsigned int u) {   // high bf16 -> f32
    return __uint_as_float(u & 0xffff0000u);
}

// ---------------------------------------------------------------------------
// Kernel 1: GEMM + sup precompute. UNCHANGED from round 5.
// ---------------------------------------------------------------------------
__global__ __launch_bounds__(256) void prep_kernel(
    const float* __restrict__ x,    // [64][NN]
    const float* __restrict__ W,    // [64][128]
    const float* __restrict__ b,    // [64]
    const float* __restrict__ dis,  // [NN][KK]
    const float* __restrict__ att_w,// [KK]
    const float* __restrict__ att_b)// [1]
{
    __shared__ float At[64][66];    // W1-W2, transposed
    __shared__ float Bt[64][66];    // W2, transposed
    __shared__ float xt[64][132];   // x tile, 128 nodes
    __shared__ float disL[128 * KK];
    __shared__ float scalerL[128];

    const int t  = threadIdx.x;
    const int n0 = blockIdx.x * 128;     // grid 391; tail block has 80 valid

    for (int i = t; i < 64 * 64; i += 256) {
        int c = i >> 6, ci = i & 63;
        float w1 = W[c * 128 + ci];
        float w2 = W[c * 128 + 64 + ci];
        At[ci][c] = w1 - w2;
        Bt[ci][c] = w2;
    }
    {
        const int q  = t & 31;           // float4 index within the 128 nodes
        const int cb = t >> 5;           // 0..7
        const float4* x4 = (const float4*)x;   // [64][12500] float4
        const int nq = (n0 >> 2) + q;
        #pragma unroll
        for (int i = 0; i < 8; i++) {
            const int ci = cb * 8 + i;
            float4 v = (nq < 12500) ? x4[ci * 12500 + nq]
                                    : float4{0.f, 0.f, 0.f, 0.f};
            *(float4*)&xt[ci][q * 4] = v;
        }
    }
    for (int i = t; i < 128 * KK; i += 256) {
        const int gi = n0 * KK + i;
        disL[i] = (gi < NN * KK) ? dis[gi] : 0.f;
    }
    __syncthreads();

    // scaler[n] = tanh(att_w . dis[n] + att_b) + 1 = 2*sigmoid(2z)
    if (t < 128) {
        float z = att_b[0];
        #pragma unroll
        for (int k = 0; k < KK; k++) z += att_w[k] * disL[t * KK + k];
        scalerL[t] = 2.f / (1.f + __expf(-2.f * z));
    }
    __syncthreads();

    // sup[n][k] = 2*sigmoid(-dis*scaler)
    for (int i = t; i < 128 * KK; i += 256) {
        const int gi = n0 * KK + i;
        if (gi < NN * KK)
            g_sup[gi] = 2.f / (1.f + __expf(disL[i] * scalerL[i / KK]));
    }

    // ---- GEMM: 2 adjacent channels x 16 nodes per thread ----
    const int c2 = t & 31;     // channel pair: channels 2*c2, 2*c2+1
    const int g  = t >> 5;     // node group 0..7 -> nodes g*16 .. g*16+15

    float aA0[16], aA1[16], aB0[16], aB1[16];
    #pragma unroll
    for (int j = 0; j < 16; j++) { aA0[j]=0.f; aA1[j]=0.f; aB0[j]=0.f; aB1[j]=0.f; }

    for (int ci = 0; ci < 64; ci++) {
        const float2 a  = *(const float2*)&At[ci][c2 * 2];
        const float2 w2 = *(const float2*)&Bt[ci][c2 * 2];
        const float4* xr = (const float4*)&xt[ci][g * 16];
        #pragma unroll
        for (int q = 0; q < 4; q++) {
            float4 xv = xr[q];
            aA0[q*4+0] += a.x*xv.x;  aA1[q*4+0] += a.y*xv.x;
            aB0[q*4+0] += w2.x*xv.x; aB1[q*4+0] += w2.y*xv.x;
            aA0[q*4+1] += a.x*xv.y;  aA1[q*4+1] += a.y*xv.y;
            aB0[q*4+1] += w2.x*xv.y; aB1[q*4+1] += w2.y*xv.y;
            aA0[q*4+2] += a.x*xv.z;  aA1[q*4+2] += a.y*xv.z;
            aB0[q*4+2] += w2.x*xv.z; aB1[q*4+2] += w2.y*xv.z;
            aA0[q*4+3] += a.x*xv.w;  aA1[q*4+3] += a.y*xv.w;
            aB0[q*4+3] += w2.x*xv.w; aB1[q*4+3] += w2.y*xv.w;
        }
    }

    // stores: channel pair c2 -> group gq = c2>>4 (ch 0-31 / 32-63), pair pp
    const float b0 = b[c2 * 2], b1 = b[c2 * 2 + 1];
    const int gq = c2 >> 4;
    const int pp = c2 & 15;
    unsigned int* poolU = (unsigned int*)g_pool;   // planes of [NN][16] uints
    const size_t pa = (size_t)(gq * 2 + 0) * NN * 16;
    const size_t pb = (size_t)(gq * 2 + 1) * NN * 16;
    #pragma unroll
    for (int j = 0; j < 16; j++) {
        const int n = n0 + g * 16 + j;
        if (n < NN) {
            poolU[pa + (size_t)n * 16 + pp] = (unsigned int)f2bf(aA0[j] + b0)
                                            | ((unsigned int)f2bf(aA1[j] + b1) << 16);
            poolU[pb + (size_t)n * 16 + pp] = (unsigned int)f2bf(aB0[j])
                                            | ((unsigned int)f2bf(aB1[j]) << 16);
        }
    }
}

// ---------------------------------------------------------------------------
// Kernel 2: pinned 2-way XCD-sliced gather, MLP-restored.
// Block = ONE group (32 ch) x 40 nodes (grid 2x1250, grp = bx&1 -> XCD pin).
// Indices/sup STAGED IN LDS (pre-scaled byte offsets, pads zeroed) -> no
// register arrays, no shfl broadcasts; per-node addressing = broadcast
// ds_reads. Gathers are uint4 (16 slots x 4 quads, 1 KB/instr, 4 instr/node);
// node PAIRS batched -> 8 independent gathers (8 KB) in flight per wave.
// Slots 20..31 are pads: offset 0, sup 0 -> contribute exactly 0 to the max
// (relu folded: m>=0, sup>=0).
// ---------------------------------------------------------------------------
__global__ __launch_bounds__(256) void edge_kernel(
    const int* __restrict__ ej,      // edge_index[0] : [NN][KK]  (x_j -> B side)
    const int* __restrict__ ei,      // edge_index[1] : [NN][KK]  (x_i -> A side)
    float* __restrict__ out)         // [64][NN]
{
    __shared__ uint2 ijL[40][32];    // (aiByte, ajByte) per (node, slot)
    __shared__ float supL[40][32];
    __shared__ float tile[40][36];   // [node][32 ch], 36-stride

    const int t    = threadIdx.x;
    const int lane = t & 63;
    const int w    = t >> 6;            // wave 0..3
    const int slot = lane >> 2;         // edge slot 0..15
    const int q    = lane & 3;          // channel quad 0..3 (8 ch each, 16 B)
    const int bx   = blockIdx.x;        // 0..2499
    const int grp  = bx & 1;            // channel group, pinned to XCD set
    const int n0   = (bx >> 1) * 40;    // node block (1250 blocks, exact)

    // ---- stage indices + sup into LDS (pads zeroed) ----
    for (int i = t; i < 40 * 32; i += 256) {
        const int s = i >> 5, se = i & 31;
        uint2 o = {0u, 0u}; float sp = 0.f;
        if (se < KK) {
            const int n = n0 + s;
            o.x = ((unsigned)__builtin_nontemporal_load(&ei[n * KK + se])) << 6;
            o.y = ((unsigned)__builtin_nontemporal_load(&ej[n * KK + se])) << 6;
            sp  = __builtin_nontemporal_load(&g_sup[n * KK + se]);
        }
        ijL[s][se]  = o;
        supL[s][se] = sp;
    }
    __syncthreads();

    const char* pA = (const char*)&g_pool[grp][0][0];
    const char* pB = (const char*)&g_pool[grp][1][0];

    #pragma unroll 1
    for (int s2 = 0; s2 < 5; s2++) {
        const int r0 = w * 10 + s2 * 2;
        const int r1 = r0 + 1;

        // broadcast ds_reads (uniform row per wave, 16 distinct 8B addrs)
        const uint2 eA0 = ijL[r0][slot];
        const uint2 eA1 = ijL[r0][16 + slot];
        const uint2 eB0 = ijL[r1][slot];
        const uint2 eB1 = ijL[r1][16 + slot];
        const float sA0 = supL[r0][slot];
        const float sA1 = supL[r0][16 + slot];
        const float sB0 = supL[r1][slot];
        const float sB1 = supL[r1][16 + slot];

        // 8 independent 1 KB gathers in flight
        const uint4 a00 = *(const uint4*)(pA + eA0.x + q * 16);
        const uint4 b00 = *(const uint4*)(pB + eA0.y + q * 16);
        const uint4 a01 = *(const uint4*)(pA + eA1.x + q * 16);
        const uint4 b01 = *(const uint4*)(pB + eA1.y + q * 16);
        const uint4 a10 = *(const uint4*)(pA + eB0.x + q * 16);
        const uint4 b10 = *(const uint4*)(pB + eB0.y + q * 16);
        const uint4 a11 = *(const uint4*)(pA + eB1.x + q * 16);
        const uint4 b11 = *(const uint4*)(pB + eB1.y + q * 16);

        float m0[8], m1[8];
        #pragma unroll
        for (int i = 0; i < 8; i++) { m0[i] = 0.f; m1[i] = 0.f; }

#define ACC(m, a, bb, sp)                                          \
        m[0] = fmaxf(m[0], (bfl(a.x) + bfl(bb.x)) * sp);           \
        m[1] = fmaxf(m[1], (bfh(a.x) + bfh(bb.x)) * sp);           \
        m[2] = fmaxf(m[2], (bfl(a.y) + bfl(bb.y)) * sp);           \
        m[3] = fmaxf(m[3], (bfh(a.y) + bfh(bb.y)) * sp);           \
        m[4] = fmaxf(m[4], (bfl(a.z) + bfl(bb.z)) * sp);           \
        m[5] = fmaxf(m[5], (bfh(a.z) + bfh(bb.z)) * sp);           \
        m[6] = fmaxf(m[6], (bfl(a.w) + bfl(bb.w)) * sp);           \
        m[7] = fmaxf(m[7], (bfh(a.w) + bfh(bb.w)) * sp);

        ACC(m0, a00, b00, sA0)
        ACC(m0, a01, b01, sA1)
        ACC(m1, a10, b10, sB0)
        ACC(m1, a11, b11, sB1)
#undef ACC

        // reduce over 16 slots = lane bits 2..5
        #pragma unroll
        for (int mask = 4; mask <= 32; mask <<= 1) {
            #pragma unroll
            for (int i = 0; i < 8; i++) {
                m0[i] = fmaxf(m0[i], __shfl_xor(m0[i], mask));
                m1[i] = fmaxf(m1[i], __shfl_xor(m1[i], mask));
            }
        }
        if (slot == 0) {
            *(float4*)&tile[r0][q * 8]     = float4{m0[0], m0[1], m0[2], m0[3]};
            *(float4*)&tile[r0][q * 8 + 4] = float4{m0[4], m0[5], m0[6], m0[7]};
            *(float4*)&tile[r1][q * 8]     = float4{m1[0], m1[1], m1[2], m1[3]};
            *(float4*)&tile[r1][q * 8 + 4] = float4{m1[4], m1[5], m1[6], m1[7]};
        }
    }
    __syncthreads();

    #pragma unroll
    for (int cn = 0; cn < 5; cn++) {
        const int c  = t >> 3;              // 0..31 channel within group
        const int nl = cn * 8 + (t & 7);    // 0..39 node within block
        __builtin_nontemporal_store(tile[nl][c],
                                    &out[(size_t)(grp * 32 + c) * NN + n0 + nl]);
    }
}

extern "C" void kernel_launch(void* const* d_in, const int* in_sizes, int n_in,
                              void* d_out, int out_size, void* d_ws, size_t ws_size,
                              hipStream_t stream) {
    const float* x     = (const float*)d_in[0];
    const int*   e     = (const int*)d_in[1];    // [2][NN][KK]
    const float* dis   = (const float*)d_in[2];
    const float* W     = (const float*)d_in[3];
    const float* b     = (const float*)d_in[4];
    const float* att_w = (const float*)d_in[5];
    const float* att_b = (const float*)d_in[6];
    float* out = (float*)d_out;

    (void)d_ws; (void)ws_size;   // intentionally unused: static __device__ scratch

    prep_kernel<<<(NN + 127) / 128, 256, 0, stream>>>(x, W, b, dis, att_w, att_b);
    edge_kernel<<<2 * (NN / 40), 256, 0, stream>>>(e, e + NN * KK, out);
}

// Round 8
// 129.223 us; speedup vs baseline: 1.1662x; 1.1662x over previous
//
#include <hip/hip_runtime.h>

#define NN 50000
#define KK 20

// Static device scratch. Unsplit node-major pool: 128 B per (node, side) =
// one full cache line per gather endpoint (transaction-rate-limited regime:
// max bytes per transaction wins; all split variants measured slower).
// NOTE: referenced ONLY inside device code — host cannot take the address
// of a __device__ symbol (R7's crash).
__device__ __align__(256) ushort g_poolA[NN * 64];   // [NN][64] bf16
__device__ __align__(256) ushort g_poolB[NN * 64];

static __device__ __forceinline__ ushort f2bf(float f) {
    unsigned int u = __float_as_uint(f);
    unsigned int r = (u + 0x7FFFu + ((u >> 16) & 1u)) >> 16;   // RNE
    return (ushort)r;
}
static __device__ __forceinline__ float bfl(unsigned int u) {   // low bf16 -> f32
    return __uint_as_float(u << 16);
}
static __device__ __forceinline__ float bfh(unsigned int u) {   // high bf16 -> f32
    return __uint_as_float(u & 0xffff0000u);
}

// ---------------------------------------------------------------------------
// Kernel 1: yA[n][c] = (W1-W2)@x + b ; yB[n][c] = W2@x, node-major bf16.
// R0 register-tile structure (2 adjacent channels x 16 nodes per thread).
// Delta: At/Bt fused into one interleaved LDS array -> hot loop does
// 1 ds_read_b128 (weights) + 4 ds_read_b128 (x) per ci. Pools written
// directly (device-side symbol reference).
// ---------------------------------------------------------------------------
__global__ __launch_bounds__(256) void prep_kernel(
    const float* __restrict__ x,   // [64][NN]
    const float* __restrict__ W,   // [64][128]
    const float* __restrict__ b)   // [64]
{
    __shared__ float ABt[64][132]; // per ci: 32 x float4 {a(2c2), a(2c2+1), w2(2c2), w2(2c2+1)}
    __shared__ float xt[64][132];  // x tile, 128 nodes

    const int t  = threadIdx.x;
    const int n0 = blockIdx.x * 128;     // grid 391; tail block has 80 valid

    for (int i = t; i < 64 * 64; i += 256) {
        int c = i >> 6, ci = i & 63;
        float w1 = W[c * 128 + ci];
        float w2 = W[c * 128 + 64 + ci];
        const int base = (c >> 1) * 4 + (c & 1);
        ABt[ci][base]     = w1 - w2;
        ABt[ci][base + 2] = w2;
    }
    {
        const int q  = t & 31;           // float4 index within the 128 nodes
        const int cb = t >> 5;           // 0..7
        const float4* x4 = (const float4*)x;   // [64][12500] float4
        const int nq = (n0 >> 2) + q;
        #pragma unroll
        for (int i = 0; i < 8; i++) {
            const int ci = cb * 8 + i;
            float4 v = (nq < 12500) ? x4[ci * 12500 + nq]
                                    : float4{0.f, 0.f, 0.f, 0.f};
            *(float4*)&xt[ci][q * 4] = v;
        }
    }
    __syncthreads();

    const int c2 = t & 31;     // channel pair: channels 2*c2, 2*c2+1
    const int g  = t >> 5;     // node group 0..7 -> nodes g*16 .. g*16+15

    float aA0[16], aA1[16], aB0[16], aB1[16];
    #pragma unroll
    for (int j = 0; j < 16; j++) { aA0[j]=0.f; aA1[j]=0.f; aB0[j]=0.f; aB1[j]=0.f; }

    for (int ci = 0; ci < 64; ci++) {
        const float4 ab = *(const float4*)&ABt[ci][c2 * 4];  // {a0,a1,w0,w1}
        const float4* xr = (const float4*)&xt[ci][g * 16];
        #pragma unroll
        for (int q = 0; q < 4; q++) {
            float4 xv = xr[q];
            aA0[q*4+0] += ab.x*xv.x;  aA1[q*4+0] += ab.y*xv.x;
            aB0[q*4+0] += ab.z*xv.x;  aB1[q*4+0] += ab.w*xv.x;
            aA0[q*4+1] += ab.x*xv.y;  aA1[q*4+1] += ab.y*xv.y;
            aB0[q*4+1] += ab.z*xv.y;  aB1[q*4+1] += ab.w*xv.y;
            aA0[q*4+2] += ab.x*xv.z;  aA1[q*4+2] += ab.y*xv.z;
            aB0[q*4+2] += ab.z*xv.z;  aB1[q*4+2] += ab.w*xv.z;
            aA0[q*4+3] += ab.x*xv.w;  aA1[q*4+3] += ab.y*xv.w;
            aB0[q*4+3] += ab.z*xv.w;  aB1[q*4+3] += ab.w*xv.w;
        }
    }

    const float b0 = b[c2 * 2], b1 = b[c2 * 2 + 1];
    unsigned int* yA32 = (unsigned int*)g_poolA;   // [NN][32] channel-pairs
    unsigned int* yB32 = (unsigned int*)g_poolB;
    #pragma unroll
    for (int j = 0; j < 16; j++) {
        const int n = n0 + g * 16 + j;
        if (n < NN) {
            yA32[n * 32 + c2] = (unsigned int)f2bf(aA0[j] + b0)
                              | ((unsigned int)f2bf(aA1[j] + b1) << 16);
            yB32[n * 32 + c2] = (unsigned int)f2bf(aB0[j])
                              | ((unsigned int)f2bf(aB1[j]) << 16);
        }
    }
}

// ---------------------------------------------------------------------------
// Kernel 2: R0-proven geometry. 16 nodes/block (grid 3125), 4 nodes/wave,
// 4 edge slots x 16 channel-quads, full 128 B/endpoint, 10 uint2 gathers per
// node, sup computed INLINE (tanh + shfl reduce are free under gather
// latency). Deltas vs R0, all bit-identical or pure-win: pre-scaled byte
// offsets; relu folded into the running max (m>=0, sup>=0).
// ---------------------------------------------------------------------------
__global__ __launch_bounds__(256) void edge_kernel(
    const int* __restrict__ ej,      // edge_index[0] : [NN][KK]  (x_j -> B pool)
    const int* __restrict__ ei,      // edge_index[1] : [NN][KK]  (x_i -> A pool)
    const float* __restrict__ dis,   // [NN][KK]
    const float* __restrict__ att_w, // [KK]
    const float* __restrict__ att_b, // [1]
    float* __restrict__ out)         // [64][NN]
{
    __shared__ float tile[16][68];

    const int t    = threadIdx.x;
    const int lane = t & 63;
    const int w    = t >> 6;            // wave 0..3
    const int g    = lane >> 4;         // edge slot 0..3
    const int l    = lane & 15;         // channel quad 0..15
    const int n0   = blockIdx.x * 16;   // grid 3125, no tail
    const int nb   = n0 + w * 4;

    const float aw = (lane < KK) ? att_w[lane] : 0.f;
    const float ab = att_b[0];

    const char* pA = (const char*)g_poolA;
    const char* pB = (const char*)g_poolB;

    float d4[4]; int offI[4], offJ[4];
    #pragma unroll
    for (int s = 0; s < 4; s++) {
        const int n = nb + s;
        float d = 0.f; int ii = 0, jj = 0;
        if (lane < KK) {
            d  = dis[n * KK + lane];
            ii = ei[n * KK + lane];
            jj = ej[n * KK + lane];
        }
        d4[s] = d;
        offI[s] = ii << 7;      // byte offset: node * 128
        offJ[s] = jj << 7;
    }

    float sup4[4];
    #pragma unroll
    for (int s = 0; s < 4; s++) {
        float p = aw * d4[s];
        #pragma unroll
        for (int off = 16; off > 0; off >>= 1) p += __shfl_down(p, off);
        // tanh(z)+1 = 2*sigmoid(2z)
        const float scaler = 2.f / (1.f + __expf(-2.f * (__shfl(p, 0) + ab)));
        sup4[s] = 2.0f / (1.0f + __expf(d4[s] * scaler));  // valid lanes < 20
    }

    #pragma unroll
    for (int s = 0; s < 4; s++) {
        float4 m = {0.f, 0.f, 0.f, 0.f};
        #pragma unroll
        for (int kb = 0; kb < 5; kb++) {
            const int   src = kb * 4 + g;       // 0..19
            const int   oi  = __shfl(offI[s], src);
            const int   oj  = __shfl(offJ[s], src);
            const float sp  = __shfl(sup4[s], src);
            const uint2 a   = *(const uint2*)(pA + oi + l * 8);
            const uint2 bb  = *(const uint2*)(pB + oj + l * 8);
            // relu folded: m>=0 and sp>=0 => fmax(m, z*sp) == fmax(m, relu(z)*sp)
            m.x = fmaxf(m.x, (bfl(a.x) + bfl(bb.x)) * sp);
            m.y = fmaxf(m.y, (bfh(a.x) + bfh(bb.x)) * sp);
            m.z = fmaxf(m.z, (bfl(a.y) + bfl(bb.y)) * sp);
            m.w = fmaxf(m.w, (bfh(a.y) + bfh(bb.y)) * sp);
        }
        #pragma unroll
        for (int mask = 16; mask <= 32; mask <<= 1) {
            m.x = fmaxf(m.x, __shfl_xor(m.x, mask));
            m.y = fmaxf(m.y, __shfl_xor(m.y, mask));
            m.z = fmaxf(m.z, __shfl_xor(m.z, mask));
            m.w = fmaxf(m.w, __shfl_xor(m.w, mask));
        }
        if (g == 0) *(float4*)&tile[w * 4 + s][l * 4] = m;
    }
    __syncthreads();

    #pragma unroll
    for (int it = 0; it < 4; it++) {
        const int c  = it * 16 + (t >> 4);
        const int nl = t & 15;
        out[(size_t)c * NN + n0 + nl] = tile[nl][c];
    }
}

extern "C" void kernel_launch(void* const* d_in, const int* in_sizes, int n_in,
                              void* d_out, int out_size, void* d_ws, size_t ws_size,
                              hipStream_t stream) {
    const float* x     = (const float*)d_in[0];
    const int*   e     = (const int*)d_in[1];    // [2][NN][KK]
    const float* dis   = (const float*)d_in[2];
    const float* W     = (const float*)d_in[3];
    const float* b     = (const float*)d_in[4];
    const float* att_w = (const float*)d_in[5];
    const float* att_b = (const float*)d_in[6];
    float* out = (float*)d_out;

    (void)d_ws; (void)ws_size;   // intentionally unused: static __device__ scratch

    prep_kernel<<<(NN + 127) / 128, 256, 0, stream>>>(x, W, b);
    edge_kernel<<<NN / 16, 256, 0, stream>>>(e, e + NN * KK, dis, att_w, att_b, out);
}